// Round 2
// baseline (1187.893 us; speedup 1.0000x reference)
//
#include <hip/hip_runtime.h>
#include <stdint.h>

typedef __bf16 bf16;
typedef bf16 bf16x8 __attribute__((ext_vector_type(8)));
typedef bf16 bf16x4 __attribute__((ext_vector_type(4)));
typedef float f32x4 __attribute__((ext_vector_type(4)));

#define DIM   1024
#define TMAX  16
#define NTPL  64
#define BATCH 2048
#define SLEN  77

__device__ __forceinline__ void gl_lds16(const void* g, void* l) {
  __builtin_amdgcn_global_load_lds(
      (const __attribute__((address_space(1))) void*)g,
      (__attribute__((address_space(3))) void*)l, 16, 0, 0);
}

__device__ __forceinline__ bf16x8 cvt8(float4 u, float4 w) {
  bf16x8 o = {(bf16)u.x, (bf16)u.y, (bf16)u.z, (bf16)u.w,
              (bf16)w.x, (bf16)w.y, (bf16)w.z, (bf16)w.w};
  return o;
}

// ---------------- bucket by time_step (1 block) ----------------
__global__ void bucket_k(const int* __restrict__ ts, int* __restrict__ perm,
                         int* __restrict__ bstart) {
  __shared__ int cnt[TMAX], base[TMAX], cur[TMAX];
  int tid = threadIdx.x;
  if (tid < TMAX) { cnt[tid] = 0; cur[tid] = 0; }
  __syncthreads();
  for (int b = tid; b < BATCH; b += 256) atomicAdd(&cnt[ts[b]], 1);
  __syncthreads();
  if (tid == 0) {
    int a = 0;
    for (int t = 0; t < TMAX; ++t) { base[t] = a; bstart[t] = a; a += cnt[t]; }
    bstart[TMAX] = a;
  }
  __syncthreads();
  for (int b = tid; b < BATCH; b += 256) {
    int t = ts[b];
    perm[base[t] + atomicAdd(&cur[t], 1)] = b;
  }
}

// textual_query (fp32) -> bf16 upper half of xcat rows (row stride 2*DIM)
__global__ void cvt_tq_k(const float* __restrict__ tq, bf16* __restrict__ xcat) {
  int idx = blockIdx.x * 256 + threadIdx.x;  // BATCH*DIM/4 units
  int b = idx >> 8, c4 = idx & 255;
  float4 v = ((const float4*)(tq + (size_t)b * DIM))[c4];
  bf16x4 o = {(bf16)v.x, (bf16)v.y, (bf16)v.z, (bf16)v.w};
  *(bf16x4*)(xcat + (size_t)b * 2 * DIM + DIM + c4 * 4) = o;
}

// ---------------- stage 1: per-t gathered GEMM, A & B fp32 converted in staging ----------------
// x1[perm] = tsent[perm] @ W1[t]^T + W1_b[t]  -> scatter into xcat[:, 0:DIM]
__global__ __launch_bounds__(256, 2) void gemm_s1(
    const float* __restrict__ tsent, const float* __restrict__ W1w,
    const float* __restrict__ W1b, const int* __restrict__ perm,
    const int* __restrict__ bstart, bf16* __restrict__ xcat) {
  const int t = blockIdx.z;
  const int s0 = bstart[t];
  const int cnt = bstart[t + 1] - s0;
  const int by = blockIdx.y;
  if (by * 128 >= cnt) return;
  __shared__ bf16 As[128 * 32];
  __shared__ bf16 Bs[128 * 32];
  const int tid = threadIdx.x;
  const int colBase = blockIdx.x * 128;
  const float* Bmat = W1w + (size_t)t * DIM * DIM;

  const float* agf[2]; const float* bgf[2];
  bf16* al[2]; bf16* bl[2];
#pragma unroll
  for (int i = 0; i < 2; ++i) {
    int j = tid + i * 256;
    int r = j >> 2, kq = j & 3;
    int lr = by * 128 + r;
    int src = perm[s0 + (lr < cnt ? lr : 0)];
    agf[i] = tsent + (size_t)src * DIM + kq * 8;
    bgf[i] = Bmat + (size_t)(colBase + r) * DIM + kq * 8;
    al[i] = As + j * 8;
    bl[i] = Bs + j * 8;
  }
  const int wave = tid >> 6, lane = tid & 63;
  const int wm = wave >> 1, wn = wave & 1;
  const int mr = lane & 15, quad = lane >> 4;

  f32x4 acc[4][4];
#pragma unroll
  for (int i = 0; i < 4; ++i)
#pragma unroll
    for (int j = 0; j < 4; ++j) acc[i][j] = (f32x4){0.f, 0.f, 0.f, 0.f};

  for (int k0 = 0; k0 < DIM; k0 += 32) {
    __syncthreads();
#pragma unroll
    for (int i = 0; i < 2; ++i) {
      float4 ua = *(const float4*)(agf[i] + k0);
      float4 wa = *(const float4*)(agf[i] + k0 + 4);
      float4 ub = *(const float4*)(bgf[i] + k0);
      float4 wb = *(const float4*)(bgf[i] + k0 + 4);
      *(bf16x8*)al[i] = cvt8(ua, wa);
      *(bf16x8*)bl[i] = cvt8(ub, wb);
    }
    __syncthreads();
    bf16x8 af[4], bfr[4];
#pragma unroll
    for (int i = 0; i < 4; ++i)
      af[i] = *(const bf16x8*)&As[(wm * 64 + i * 16 + mr) * 32 + quad * 8];
#pragma unroll
    for (int j = 0; j < 4; ++j)
      bfr[j] = *(const bf16x8*)&Bs[(wn * 64 + j * 16 + mr) * 32 + quad * 8];
#pragma unroll
    for (int i = 0; i < 4; ++i)
#pragma unroll
      for (int j = 0; j < 4; ++j)
        acc[i][j] = __builtin_amdgcn_mfma_f32_16x16x32_bf16(af[i], bfr[j], acc[i][j], 0, 0, 0);
  }

  const int r0 = quad * 4;
#pragma unroll
  for (int i = 0; i < 4; ++i) {
    int lr = by * 128 + wm * 64 + i * 16 + r0;
#pragma unroll
    for (int j = 0; j < 4; ++j) {
      int gn = colBase + wn * 64 + j * 16 + mr;
      float bv = W1b[t * DIM + gn];
#pragma unroll
      for (int r = 0; r < 4; ++r) {
        if (lr + r < cnt) {
          int bidx = perm[s0 + lr + r];
          xcat[(size_t)bidx * 2 * DIM + gn] = (bf16)(acc[i][j][r] + bv);
        }
      }
    }
  }
}

// ---------------- bf16-A x fp32-B^T GEMM: C[M,1024] = A[M,K] * B[1024,K]^T + bias ----------------
// B converted to bf16 during LDS staging. 128x128 tile, full tiles only.
__global__ __launch_bounds__(256, 2) void gemm_bt_bf(
    const bf16* __restrict__ A, int lda, const float* __restrict__ Bf, int ldb,
    const float* __restrict__ bias, bf16* __restrict__ C, int ldc,
    float* __restrict__ Cf, int K, int relu) {
  __shared__ bf16 As[128 * 32];
  __shared__ bf16 Bs[128 * 32];
  const int tid = threadIdx.x;
  const int rowBase = blockIdx.y * 128, colBase = blockIdx.x * 128;

  const bf16* ag[2]; const float* bgf[2];
  bf16* al[2]; bf16* bl[2];
#pragma unroll
  for (int i = 0; i < 2; ++i) {
    int j = tid + i * 256;
    int r = j >> 2, kq = j & 3;
    ag[i] = A + (size_t)(rowBase + r) * lda + kq * 8;
    bgf[i] = Bf + (size_t)(colBase + r) * ldb + kq * 8;
    al[i] = As + j * 8;
    bl[i] = Bs + j * 8;
  }
  const int wave = tid >> 6, lane = tid & 63;
  const int wm = wave >> 1, wn = wave & 1;
  const int mr = lane & 15, quad = lane >> 4;

  f32x4 acc[4][4];
#pragma unroll
  for (int i = 0; i < 4; ++i)
#pragma unroll
    for (int j = 0; j < 4; ++j) acc[i][j] = (f32x4){0.f, 0.f, 0.f, 0.f};

  for (int k0 = 0; k0 < K; k0 += 32) {
    __syncthreads();
#pragma unroll
    for (int i = 0; i < 2; ++i) {
      gl_lds16(ag[i] + k0, al[i]);
      float4 ub = *(const float4*)(bgf[i] + k0);
      float4 wb = *(const float4*)(bgf[i] + k0 + 4);
      *(bf16x8*)bl[i] = cvt8(ub, wb);
    }
    __syncthreads();
    bf16x8 af[4], bfr[4];
#pragma unroll
    for (int i = 0; i < 4; ++i)
      af[i] = *(const bf16x8*)&As[(wm * 64 + i * 16 + mr) * 32 + quad * 8];
#pragma unroll
    for (int j = 0; j < 4; ++j)
      bfr[j] = *(const bf16x8*)&Bs[(wn * 64 + j * 16 + mr) * 32 + quad * 8];
#pragma unroll
    for (int i = 0; i < 4; ++i)
#pragma unroll
      for (int j = 0; j < 4; ++j)
        acc[i][j] = __builtin_amdgcn_mfma_f32_16x16x32_bf16(af[i], bfr[j], acc[i][j], 0, 0, 0);
  }

  const int r0 = quad * 4;
#pragma unroll
  for (int i = 0; i < 4; ++i) {
    int gm = rowBase + wm * 64 + i * 16 + r0;
#pragma unroll
    for (int j = 0; j < 4; ++j) {
      int gn = colBase + wn * 64 + j * 16 + mr;
      float bv = bias[gn];
#pragma unroll
      for (int r = 0; r < 4; ++r) {
        float v = acc[i][j][r] + bv;
        if (relu) v = fmaxf(v, 0.f);
        C[(size_t)(gm + r) * ldc + gn] = (bf16)v;
        if (Cf) Cf[(size_t)(gm + r) * ldc + gn] = v;
      }
    }
  }
}

// ---------------- fused m3 GEMM (N=64) + softmax -> template_distribution ----------------
__global__ __launch_bounds__(256, 2) void gemm_m3_sm(
    const bf16* __restrict__ A, const float* __restrict__ Bf,
    const float* __restrict__ bias, float* __restrict__ out) {
  __shared__ bf16 As[128 * 32];
  __shared__ bf16 Bs[64 * 32];
  __shared__ float lg[128][NTPL + 1];
  const int tid = threadIdx.x;
  const int rowBase = blockIdx.x * 128;

  const bf16* ag[2]; bf16* al[2];
#pragma unroll
  for (int i = 0; i < 2; ++i) {
    int j = tid + i * 256;
    int r = j >> 2, kq = j & 3;
    ag[i] = A + (size_t)(rowBase + r) * DIM + kq * 8;
    al[i] = As + j * 8;
  }
  const float* bgf = Bf + (size_t)(tid >> 2) * DIM + (tid & 3) * 8;
  bf16* bl = Bs + tid * 8;

  const int wave = tid >> 6, lane = tid & 63;
  const int mr = lane & 15, quad = lane >> 4;

  f32x4 acc[2][4];
#pragma unroll
  for (int i = 0; i < 2; ++i)
#pragma unroll
    for (int j = 0; j < 4; ++j) acc[i][j] = (f32x4){0.f, 0.f, 0.f, 0.f};

  for (int k0 = 0; k0 < DIM; k0 += 32) {
    __syncthreads();
    gl_lds16(ag[0] + k0, al[0]);
    gl_lds16(ag[1] + k0, al[1]);
    {
      float4 ub = *(const float4*)(bgf + k0);
      float4 wb = *(const float4*)(bgf + k0 + 4);
      *(bf16x8*)bl = cvt8(ub, wb);
    }
    __syncthreads();
    bf16x8 af[2], bfr[4];
#pragma unroll
    for (int i = 0; i < 2; ++i)
      af[i] = *(const bf16x8*)&As[(wave * 32 + i * 16 + mr) * 32 + quad * 8];
#pragma unroll
    for (int j = 0; j < 4; ++j)
      bfr[j] = *(const bf16x8*)&Bs[(j * 16 + mr) * 32 + quad * 8];
#pragma unroll
    for (int i = 0; i < 2; ++i)
#pragma unroll
      for (int j = 0; j < 4; ++j)
        acc[i][j] = __builtin_amdgcn_mfma_f32_16x16x32_bf16(af[i], bfr[j], acc[i][j], 0, 0, 0);
  }

#pragma unroll
  for (int i = 0; i < 2; ++i)
#pragma unroll
    for (int j = 0; j < 4; ++j) {
      float bv = bias[j * 16 + mr];
#pragma unroll
      for (int r = 0; r < 4; ++r)
        lg[wave * 32 + i * 16 + quad * 4 + r][j * 16 + mr] = acc[i][j][r] + bv;
    }
  __syncthreads();
  for (int row = wave; row < 128; row += 4) {
    float v = lg[row][lane];
    float mx = v;
#pragma unroll
    for (int o = 32; o; o >>= 1) mx = fmaxf(mx, __shfl_xor(mx, o));
    float e = __expf(v - mx);
    float s = e;
#pragma unroll
    for (int o = 32; o; o >>= 1) s += __shfl_xor(s, o);
    out[(size_t)(rowBase + row) * NTPL + lane] = e / s;
  }
}

// ---------------- fused word attention: wave-per-word online softmax, no loop barriers ----------------
__global__ __launch_bounds__(256) void attn_k(
    const float* __restrict__ x, const float* __restrict__ attn_w,
    const float* __restrict__ attn_b, const float* __restrict__ feats,
    float* __restrict__ words, float* __restrict__ ct) {
  const int b = blockIdx.x;
  const int tid = threadIdx.x;
  const int wave = tid >> 6, lane = tid & 63;
  const float* fb = feats + (size_t)b * SLEN * DIM;

  float4 v[4], acc[4];
#pragma unroll
  for (int q = 0; q < 4; ++q) {
    float4 xv = *(const float4*)(x + (size_t)b * DIM + q * 256 + lane * 4);
    float4 aw = *(const float4*)(attn_w + q * 256 + lane * 4);
    v[q].x = xv.x * aw.x; v[q].y = xv.y * aw.y;
    v[q].z = xv.z * aw.z; v[q].w = xv.w * aw.w;
    acc[q] = make_float4(0.f, 0.f, 0.f, 0.f);
  }
  const float ab = attn_b[0];

  __shared__ float sc[SLEN];
  __shared__ float sm[4], sl[4];
  __shared__ float sacc[4][DIM];

  float m = -1e30f, l = 0.f;
  for (int s = wave; s < SLEN; s += 4) {
    const float* fr = fb + (size_t)s * DIM;
    float4 f[4];
    float p = 0.f;
#pragma unroll
    for (int q = 0; q < 4; ++q) {
      f[q] = *(const float4*)(fr + q * 256 + lane * 4);
      p += f[q].x * v[q].x + f[q].y * v[q].y + f[q].z * v[q].z + f[q].w * v[q].w;
    }
#pragma unroll
    for (int o = 32; o; o >>= 1) p += __shfl_xor(p, o);
    float score = p + ab;
    if (lane == 0) sc[s] = score;
    float mn = fmaxf(m, score);
    float scale = __expf(m - mn);
    float w = __expf(score - mn);
    l = l * scale + w;
#pragma unroll
    for (int q = 0; q < 4; ++q) {
      acc[q].x = acc[q].x * scale + w * f[q].x;
      acc[q].y = acc[q].y * scale + w * f[q].y;
      acc[q].z = acc[q].z * scale + w * f[q].z;
      acc[q].w = acc[q].w * scale + w * f[q].w;
    }
    m = mn;
  }
  if (lane == 0) { sm[wave] = m; sl[wave] = l; }
#pragma unroll
  for (int q = 0; q < 4; ++q)
    *(float4*)&sacc[wave][q * 256 + lane * 4] = acc[q];
  __syncthreads();

  float M = fmaxf(fmaxf(sm[0], sm[1]), fmaxf(sm[2], sm[3]));
  float e0 = __expf(sm[0] - M), e1 = __expf(sm[1] - M);
  float e2 = __expf(sm[2] - M), e3 = __expf(sm[3] - M);
  float L = sl[0] * e0 + sl[1] * e1 + sl[2] * e2 + sl[3] * e3;
  float invL = 1.f / L;

  if (tid < SLEN) words[(size_t)b * SLEN + tid] = __expf(sc[tid] - M) * invL;

  float4 a0 = *(float4*)&sacc[0][tid * 4];
  float4 a1 = *(float4*)&sacc[1][tid * 4];
  float4 a2 = *(float4*)&sacc[2][tid * 4];
  float4 a3 = *(float4*)&sacc[3][tid * 4];
  float4 o;
  o.x = (a0.x * e0 + a1.x * e1 + a2.x * e2 + a3.x * e3) * invL;
  o.y = (a0.y * e0 + a1.y * e1 + a2.y * e2 + a3.y * e3) * invL;
  o.z = (a0.z * e0 + a1.z * e1 + a2.z * e2 + a3.z * e3) * invL;
  o.w = (a0.w * e0 + a1.w * e1 + a2.w * e2 + a3.w * e3) * invL;
  *(float4*)(ct + (size_t)b * DIM + tid * 4) = o;
}

extern "C" void kernel_launch(void* const* d_in, const int* in_sizes, int n_in,
                              void* d_out, int out_size, void* d_ws, size_t ws_size,
                              hipStream_t stream) {
  const float* feats = (const float*)d_in[0];
  const float* tsent = (const float*)d_in[1];
  const float* tq    = (const float*)d_in[2];
  const int*   tstep = (const int*)d_in[3];
  const float* W1w = (const float*)d_in[4];
  const float* W1b = (const float*)d_in[5];
  const float* W2w = (const float*)d_in[6];
  const float* W2b = (const float*)d_in[7];
  const float* m1w = (const float*)d_in[8];
  const float* m1b = (const float*)d_in[9];
  const float* m2w = (const float*)d_in[10];
  const float* m2b = (const float*)d_in[11];
  const float* m3w = (const float*)d_in[12];
  const float* m3b = (const float*)d_in[13];
  const float* attw = (const float*)d_in[14];
  const float* attb = (const float*)d_in[15];

  char* p = (char*)d_ws;
  auto alloc = [&](size_t bytes) { char* q = p; p += (bytes + 255) & ~(size_t)255; return q; };
  int*  perm   = (int*)alloc(BATCH * 4);
  int*  bstart = (int*)alloc(17 * 4);
  bf16* xcat = (bf16*)alloc((size_t)BATCH * 2 * DIM * 2);  // [x1 | tq] bf16, lda=2048
  bf16* xbf  = (bf16*)alloc((size_t)BATCH * DIM * 2);
  float* xf  = (float*)alloc((size_t)BATCH * DIM * 4);     // fp32 x for attention
  bf16* h1   = (bf16*)alloc((size_t)BATCH * DIM * 2);
  bf16* h2   = (bf16*)alloc((size_t)BATCH * DIM * 2);

  float* out_td = (float*)d_out;
  float* out_w  = out_td + (size_t)BATCH * NTPL;
  float* out_ct = out_w + (size_t)BATCH * SLEN;

  bucket_k<<<1, 256, 0, stream>>>(tstep, perm, bstart);
  cvt_tq_k<<<(BATCH * DIM) / 1024, 256, 0, stream>>>(tq, xcat);
  // x1 (gathered, per-t, fp32 weights cvt in staging) -> xcat[:, 0:DIM]
  gemm_s1<<<dim3(DIM / 128, BATCH / 128, TMAX), 256, 0, stream>>>(
      tsent, W1w, W1b, perm, bstart, xcat);
  // x = xcat @ W2^T + b (K=2048); bf16 out + fp32 copy for attention
  gemm_bt_bf<<<dim3(DIM / 128, BATCH / 128), 256, 0, stream>>>(
      xcat, 2 * DIM, W2w, 2 * DIM, W2b, xbf, DIM, xf, 2 * DIM, 0);
  // attention (depends only on xf) — biggest kernel, launch next
  attn_k<<<BATCH, 256, 0, stream>>>(xf, attw, attb, feats, out_w, out_ct);
  // h1 = relu(x @ m1^T + b)
  gemm_bt_bf<<<dim3(DIM / 128, BATCH / 128), 256, 0, stream>>>(
      xbf, DIM, m1w, DIM, m1b, h1, DIM, nullptr, DIM, 1);
  // h2 = relu(h1 @ m2^T + b)
  gemm_bt_bf<<<dim3(DIM / 128, BATCH / 128), 256, 0, stream>>>(
      h1, DIM, m2w, DIM, m2b, h2, DIM, nullptr, DIM, 1);
  // template_distribution = softmax(h2 @ m3^T + b)
  gemm_m3_sm<<<BATCH / 128, 256, 0, stream>>>(h2, m3w, m3b, out_td);
}

// Round 3
// 1105.228 us; speedup vs baseline: 1.0748x; 1.0748x over previous
//
#include <hip/hip_runtime.h>
#include <stdint.h>

typedef __bf16 bf16;
typedef bf16 bf16x8 __attribute__((ext_vector_type(8)));
typedef bf16 bf16x4 __attribute__((ext_vector_type(4)));
typedef float f32x4 __attribute__((ext_vector_type(4)));

#define DIM   1024
#define TMAX  16
#define NTPL  64
#define BATCH 2048
#define SLEN  77

__device__ __forceinline__ void gl_lds16(const void* g, void* l) {
  __builtin_amdgcn_global_load_lds(
      (const __attribute__((address_space(1))) void*)g,
      (__attribute__((address_space(3))) void*)l, 16, 0, 0);
}

__device__ __forceinline__ bf16x8 cvt8(float4 u, float4 w) {
  bf16x8 o = {(bf16)u.x, (bf16)u.y, (bf16)u.z, (bf16)u.w,
              (bf16)w.x, (bf16)w.y, (bf16)w.z, (bf16)w.w};
  return o;
}

// ---------------- prep: block 0 buckets time_step; blocks 1.. convert tq -> xcat upper ----------------
__global__ void prep_k(const int* __restrict__ ts, int* __restrict__ perm,
                       int* __restrict__ bstart, const float* __restrict__ tq,
                       bf16* __restrict__ xcat) {
  int tid = threadIdx.x;
  if (blockIdx.x == 0) {
    __shared__ int cnt[TMAX], base[TMAX], cur[TMAX];
    if (tid < TMAX) { cnt[tid] = 0; cur[tid] = 0; }
    __syncthreads();
    for (int b = tid; b < BATCH; b += 256) atomicAdd(&cnt[ts[b]], 1);
    __syncthreads();
    if (tid == 0) {
      int a = 0;
      for (int t = 0; t < TMAX; ++t) { base[t] = a; bstart[t] = a; a += cnt[t]; }
      bstart[TMAX] = a;
    }
    __syncthreads();
    for (int b = tid; b < BATCH; b += 256) {
      int t = ts[b];
      perm[base[t] + atomicAdd(&cur[t], 1)] = b;
    }
  } else {
    int idx = (blockIdx.x - 1) * 256 + tid;  // BATCH*DIM/4 units
    int b = idx >> 8, c4 = idx & 255;
    float4 v = ((const float4*)(tq + (size_t)b * DIM))[c4];
    bf16x4 o = {(bf16)v.x, (bf16)v.y, (bf16)v.z, (bf16)v.w};
    *(bf16x4*)(xcat + (size_t)b * 2 * DIM + DIM + c4 * 4) = o;
  }
}

// ---------------- 64x64-tile bf16-A x fp32-B^T GEMM + bias (+relu, + optional fp32 copy) ----------------
// 2 blocks/CU at grid 512: cross-block wave overlap hides staging + barrier latency.
__global__ __launch_bounds__(256, 2) void gemm64_k(
    const bf16* __restrict__ A, int lda, const float* __restrict__ Bf, int ldb,
    const float* __restrict__ bias, bf16* __restrict__ C, int ldc,
    float* __restrict__ Cf, int K, int relu) {
  __shared__ bf16 As[64 * 32];
  __shared__ bf16 Bs[64 * 32];
  const int tid = threadIdx.x;
  const int rowBase = blockIdx.y * 64, colBase = blockIdx.x * 64;
  const int r = tid >> 2, kq = tid & 3;
  const bf16* ag = A + (size_t)(rowBase + r) * lda + kq * 8;
  bf16* al = As + tid * 8;
  const float* bg = Bf + (size_t)(colBase + r) * ldb + kq * 8;
  bf16* bl = Bs + tid * 8;
  const int wave = tid >> 6, lane = tid & 63;
  const int wm = wave >> 1, wn = wave & 1;
  const int mr = lane & 15, quad = lane >> 4;

  f32x4 acc[2][2];
#pragma unroll
  for (int i = 0; i < 2; ++i)
#pragma unroll
    for (int j = 0; j < 2; ++j) acc[i][j] = (f32x4){0.f, 0.f, 0.f, 0.f};

  for (int k0 = 0; k0 < K; k0 += 32) {
    __syncthreads();
    gl_lds16(ag + k0, al);
    float4 ub = *(const float4*)(bg + k0);
    float4 wb = *(const float4*)(bg + k0 + 4);
    *(bf16x8*)bl = cvt8(ub, wb);
    __syncthreads();
    bf16x8 af[2], bfr[2];
#pragma unroll
    for (int i = 0; i < 2; ++i)
      af[i] = *(const bf16x8*)&As[(wm * 32 + i * 16 + mr) * 32 + quad * 8];
#pragma unroll
    for (int j = 0; j < 2; ++j)
      bfr[j] = *(const bf16x8*)&Bs[(wn * 32 + j * 16 + mr) * 32 + quad * 8];
#pragma unroll
    for (int i = 0; i < 2; ++i)
#pragma unroll
      for (int j = 0; j < 2; ++j)
        acc[i][j] = __builtin_amdgcn_mfma_f32_16x16x32_bf16(af[i], bfr[j], acc[i][j], 0, 0, 0);
  }

#pragma unroll
  for (int i = 0; i < 2; ++i) {
    int gm = rowBase + wm * 32 + i * 16 + quad * 4;
#pragma unroll
    for (int j = 0; j < 2; ++j) {
      int gn = colBase + wn * 32 + j * 16 + mr;
      float bv = bias[gn];
#pragma unroll
      for (int r2 = 0; r2 < 4; ++r2) {
        float v = acc[i][j][r2] + bv;
        if (relu) v = fmaxf(v, 0.f);
        C[(size_t)(gm + r2) * ldc + gn] = (bf16)v;
        if (Cf) Cf[(size_t)(gm + r2) * ldc + gn] = v;
      }
    }
  }
}

// ---------------- stage 1: per-t gathered 64x64 GEMM (A,B fp32 cvt in staging), scatter out ----------------
__global__ __launch_bounds__(256, 2) void gemm_s1_k(
    const float* __restrict__ tsent, const float* __restrict__ W1w,
    const float* __restrict__ W1b, const int* __restrict__ perm,
    const int* __restrict__ bstart, bf16* __restrict__ xcat) {
  const int t = blockIdx.z;
  const int s0 = bstart[t];
  const int cnt = bstart[t + 1] - s0;
  const int by = blockIdx.y;
  if (by * 64 >= cnt) return;
  __shared__ bf16 As[64 * 32];
  __shared__ bf16 Bs[64 * 32];
  const int tid = threadIdx.x;
  const int colBase = blockIdx.x * 64;
  const int r = tid >> 2, kq = tid & 3;
  int lr0 = by * 64 + r;
  int src = perm[s0 + (lr0 < cnt ? lr0 : cnt - 1)];
  const float* agf = tsent + (size_t)src * DIM + kq * 8;
  const float* bgf = W1w + ((size_t)t << 20) + (size_t)(colBase + r) * DIM + kq * 8;
  bf16* al = As + tid * 8;
  bf16* bl = Bs + tid * 8;
  const int wave = tid >> 6, lane = tid & 63;
  const int wm = wave >> 1, wn = wave & 1;
  const int mr = lane & 15, quad = lane >> 4;

  f32x4 acc[2][2];
#pragma unroll
  for (int i = 0; i < 2; ++i)
#pragma unroll
    for (int j = 0; j < 2; ++j) acc[i][j] = (f32x4){0.f, 0.f, 0.f, 0.f};

  for (int k0 = 0; k0 < DIM; k0 += 32) {
    __syncthreads();
    float4 ua = *(const float4*)(agf + k0);
    float4 wa = *(const float4*)(agf + k0 + 4);
    float4 ub = *(const float4*)(bgf + k0);
    float4 wb = *(const float4*)(bgf + k0 + 4);
    *(bf16x8*)al = cvt8(ua, wa);
    *(bf16x8*)bl = cvt8(ub, wb);
    __syncthreads();
    bf16x8 af[2], bfr[2];
#pragma unroll
    for (int i = 0; i < 2; ++i)
      af[i] = *(const bf16x8*)&As[(wm * 32 + i * 16 + mr) * 32 + quad * 8];
#pragma unroll
    for (int j = 0; j < 2; ++j)
      bfr[j] = *(const bf16x8*)&Bs[(wn * 32 + j * 16 + mr) * 32 + quad * 8];
#pragma unroll
    for (int i = 0; i < 2; ++i)
#pragma unroll
      for (int j = 0; j < 2; ++j)
        acc[i][j] = __builtin_amdgcn_mfma_f32_16x16x32_bf16(af[i], bfr[j], acc[i][j], 0, 0, 0);
  }

#pragma unroll
  for (int i = 0; i < 2; ++i) {
#pragma unroll
    for (int j = 0; j < 2; ++j) {
      int gn = colBase + wn * 32 + j * 16 + mr;
      float bv = W1b[t * DIM + gn];
#pragma unroll
      for (int r2 = 0; r2 < 4; ++r2) {
        int lr = by * 64 + wm * 32 + i * 16 + quad * 4 + r2;
        if (lr < cnt) {
          int bidx = perm[s0 + lr];
          xcat[(size_t)bidx * 2 * DIM + gn] = (bf16)(acc[i][j][r2] + bv);
        }
      }
    }
  }
}

// ---------------- m3 (64x64, N=64) + fused softmax -> template_distribution ----------------
__global__ __launch_bounds__(256, 2) void gemm_m3_sm(
    const bf16* __restrict__ A, const float* __restrict__ Bf,
    const float* __restrict__ bias, float* __restrict__ out) {
  __shared__ bf16 As[64 * 32];
  __shared__ bf16 Bs[64 * 32];
  __shared__ float lg[64][NTPL + 1];
  const int tid = threadIdx.x;
  const int rowBase = blockIdx.x * 64;
  const int r = tid >> 2, kq = tid & 3;
  const bf16* ag = A + (size_t)(rowBase + r) * DIM + kq * 8;
  bf16* al = As + tid * 8;
  const float* bg = Bf + (size_t)r * DIM + kq * 8;
  bf16* bl = Bs + tid * 8;
  const int wave = tid >> 6, lane = tid & 63;
  const int wm = wave >> 1, wn = wave & 1;
  const int mr = lane & 15, quad = lane >> 4;

  f32x4 acc[2][2];
#pragma unroll
  for (int i = 0; i < 2; ++i)
#pragma unroll
    for (int j = 0; j < 2; ++j) acc[i][j] = (f32x4){0.f, 0.f, 0.f, 0.f};

  for (int k0 = 0; k0 < DIM; k0 += 32) {
    __syncthreads();
    gl_lds16(ag + k0, al);
    float4 ub = *(const float4*)(bg + k0);
    float4 wb = *(const float4*)(bg + k0 + 4);
    *(bf16x8*)bl = cvt8(ub, wb);
    __syncthreads();
    bf16x8 af[2], bfr[2];
#pragma unroll
    for (int i = 0; i < 2; ++i)
      af[i] = *(const bf16x8*)&As[(wm * 32 + i * 16 + mr) * 32 + quad * 8];
#pragma unroll
    for (int j = 0; j < 2; ++j)
      bfr[j] = *(const bf16x8*)&Bs[(wn * 32 + j * 16 + mr) * 32 + quad * 8];
#pragma unroll
    for (int i = 0; i < 2; ++i)
#pragma unroll
      for (int j = 0; j < 2; ++j)
        acc[i][j] = __builtin_amdgcn_mfma_f32_16x16x32_bf16(af[i], bfr[j], acc[i][j], 0, 0, 0);
  }

#pragma unroll
  for (int i = 0; i < 2; ++i)
#pragma unroll
    for (int j = 0; j < 2; ++j)
#pragma unroll
      for (int r2 = 0; r2 < 4; ++r2)
        lg[wm * 32 + i * 16 + quad * 4 + r2][wn * 32 + j * 16 + mr] = acc[i][j][r2];
  __syncthreads();
  for (int row = wave; row < 64; row += 4) {
    float v = lg[row][lane] + bias[lane];
    float mx = v;
#pragma unroll
    for (int o = 32; o; o >>= 1) mx = fmaxf(mx, __shfl_xor(mx, o));
    float e = __expf(v - mx);
    float s = e;
#pragma unroll
    for (int o = 32; o; o >>= 1) s += __shfl_xor(s, o);
    out[(size_t)(rowBase + row) * NTPL + lane] = e / s;
  }
}

// ---------------- fused word attention: wave-per-word online softmax, no loop barriers ----------------
__global__ __launch_bounds__(256) void attn_k(
    const float* __restrict__ x, const float* __restrict__ attn_w,
    const float* __restrict__ attn_b, const float* __restrict__ feats,
    float* __restrict__ words, float* __restrict__ ct) {
  const int b = blockIdx.x;
  const int tid = threadIdx.x;
  const int wave = tid >> 6, lane = tid & 63;
  const float* fb = feats + (size_t)b * SLEN * DIM;

  float4 v[4], acc[4];
#pragma unroll
  for (int q = 0; q < 4; ++q) {
    float4 xv = *(const float4*)(x + (size_t)b * DIM + q * 256 + lane * 4);
    float4 aw = *(const float4*)(attn_w + q * 256 + lane * 4);
    v[q].x = xv.x * aw.x; v[q].y = xv.y * aw.y;
    v[q].z = xv.z * aw.z; v[q].w = xv.w * aw.w;
    acc[q] = make_float4(0.f, 0.f, 0.f, 0.f);
  }
  const float ab = attn_b[0];

  __shared__ float sc[SLEN];
  __shared__ float sm[4], sl[4];
  __shared__ float sacc[4][DIM];

  float m = -1e30f, l = 0.f;
  for (int s = wave; s < SLEN; s += 4) {
    const float* fr = fb + (size_t)s * DIM;
    float4 f[4];
    float p = 0.f;
#pragma unroll
    for (int q = 0; q < 4; ++q) {
      f[q] = *(const float4*)(fr + q * 256 + lane * 4);
      p += f[q].x * v[q].x + f[q].y * v[q].y + f[q].z * v[q].z + f[q].w * v[q].w;
    }
#pragma unroll
    for (int o = 32; o; o >>= 1) p += __shfl_xor(p, o);
    float score = p + ab;
    if (lane == 0) sc[s] = score;
    float mn = fmaxf(m, score);
    float scale = __expf(m - mn);
    float w = __expf(score - mn);
    l = l * scale + w;
#pragma unroll
    for (int q = 0; q < 4; ++q) {
      acc[q].x = acc[q].x * scale + w * f[q].x;
      acc[q].y = acc[q].y * scale + w * f[q].y;
      acc[q].z = acc[q].z * scale + w * f[q].z;
      acc[q].w = acc[q].w * scale + w * f[q].w;
    }
    m = mn;
  }
  if (lane == 0) { sm[wave] = m; sl[wave] = l; }
#pragma unroll
  for (int q = 0; q < 4; ++q)
    *(float4*)&sacc[wave][q * 256 + lane * 4] = acc[q];
  __syncthreads();

  float M = fmaxf(fmaxf(sm[0], sm[1]), fmaxf(sm[2], sm[3]));
  float e0 = __expf(sm[0] - M), e1 = __expf(sm[1] - M);
  float e2 = __expf(sm[2] - M), e3 = __expf(sm[3] - M);
  float L = sl[0] * e0 + sl[1] * e1 + sl[2] * e2 + sl[3] * e3;
  float invL = 1.f / L;

  if (tid < SLEN) words[(size_t)b * SLEN + tid] = __expf(sc[tid] - M) * invL;

  float4 a0 = *(float4*)&sacc[0][tid * 4];
  float4 a1 = *(float4*)&sacc[1][tid * 4];
  float4 a2 = *(float4*)&sacc[2][tid * 4];
  float4 a3 = *(float4*)&sacc[3][tid * 4];
  float4 o;
  o.x = (a0.x * e0 + a1.x * e1 + a2.x * e2 + a3.x * e3) * invL;
  o.y = (a0.y * e0 + a1.y * e1 + a2.y * e2 + a3.y * e3) * invL;
  o.z = (a0.z * e0 + a1.z * e1 + a2.z * e2 + a3.z * e3) * invL;
  o.w = (a0.w * e0 + a1.w * e1 + a2.w * e2 + a3.w * e3) * invL;
  *(float4*)(ct + (size_t)b * DIM + tid * 4) = o;
}

extern "C" void kernel_launch(void* const* d_in, const int* in_sizes, int n_in,
                              void* d_out, int out_size, void* d_ws, size_t ws_size,
                              hipStream_t stream) {
  const float* feats = (const float*)d_in[0];
  const float* tsent = (const float*)d_in[1];
  const float* tq    = (const float*)d_in[2];
  const int*   tstep = (const int*)d_in[3];
  const float* W1w = (const float*)d_in[4];
  const float* W1b = (const float*)d_in[5];
  const float* W2w = (const float*)d_in[6];
  const float* W2b = (const float*)d_in[7];
  const float* m1w = (const float*)d_in[8];
  const float* m1b = (const float*)d_in[9];
  const float* m2w = (const float*)d_in[10];
  const float* m2b = (const float*)d_in[11];
  const float* m3w = (const float*)d_in[12];
  const float* m3b = (const float*)d_in[13];
  const float* attw = (const float*)d_in[14];
  const float* attb = (const float*)d_in[15];

  char* p = (char*)d_ws;
  auto alloc = [&](size_t bytes) { char* q = p; p += (bytes + 255) & ~(size_t)255; return q; };
  int*  perm   = (int*)alloc(BATCH * 4);
  int*  bstart = (int*)alloc(17 * 4);
  bf16* xcat = (bf16*)alloc((size_t)BATCH * 2 * DIM * 2);  // [x1 | tq] bf16, lda=2048
  bf16* xbf  = (bf16*)alloc((size_t)BATCH * DIM * 2);
  float* xf  = (float*)alloc((size_t)BATCH * DIM * 4);     // fp32 x for attention
  bf16* h1   = (bf16*)alloc((size_t)BATCH * DIM * 2);
  bf16* h2   = (bf16*)alloc((size_t)BATCH * DIM * 2);

  float* out_td = (float*)d_out;
  float* out_w  = out_td + (size_t)BATCH * NTPL;
  float* out_ct = out_w + (size_t)BATCH * SLEN;

  // bucket time_step + convert tq into xcat upper half (one launch)
  prep_k<<<1 + (BATCH * DIM) / 1024, 256, 0, stream>>>(tstep, perm, bstart, tq, xcat);
  // x1 (gathered per-t) -> xcat[:, 0:DIM]
  gemm_s1_k<<<dim3(DIM / 64, BATCH / 64, TMAX), 256, 0, stream>>>(
      tsent, W1w, W1b, perm, bstart, xcat);
  // x = xcat @ W2^T + b (K=2048); bf16 out + fp32 copy for attention
  gemm64_k<<<dim3(DIM / 64, BATCH / 64), 256, 0, stream>>>(
      xcat, 2 * DIM, W2w, 2 * DIM, W2b, xbf, DIM, xf, 2 * DIM, 0);
  // attention (depends only on xf) — longest kernel, launch next
  attn_k<<<BATCH, 256, 0, stream>>>(xf, attw, attb, feats, out_w, out_ct);
  // h1 = relu(x @ m1^T + b)
  gemm64_k<<<dim3(DIM / 64, BATCH / 64), 256, 0, stream>>>(
      xbf, DIM, m1w, DIM, m1b, h1, DIM, nullptr, DIM, 1);
  // h2 = relu(h1 @ m2^T + b)
  gemm64_k<<<dim3(DIM / 64, BATCH / 64), 256, 0, stream>>>(
      h1, DIM, m2w, DIM, m2b, h2, DIM, nullptr, DIM, 1);
  // template_distribution = softmax(h2 @ m3^T + b)
  gemm_m3_sm<<<BATCH / 64, 256, 0, stream>>>(h2, m3w, m3b, out_td);
}